// Round 9
// baseline (580.215 us; speedup 1.0000x reference)
//
#include <hip/hip_runtime.h>
#include <hip/hip_cooperative_groups.h>
#include <math.h>

namespace cg = cooperative_groups;

#define NB 2
#define NCH 192
#define NH 48
#define NW 48
#define NL 2304
#define NK 4
#define NN 16
#define NR 12
#define ND 44
#define CLEN 24
#define NCHUNK 96                   // NL / CLEN
#define GRID 768                    // NB*NK*NCHUNK; 3 blocks/CU
#define BLK 256

// workspace float sizes
#define SZ_XT   (NB * NCH * NL)                 // 884736
#define SZ_UT0  (NB * NL * NCH)                 // 884736
#define SZ_CB   (NB * NK * NL * NN)             // 294912
#define SZ_CUMS (NB * NK * NL * NCH)            // 3538944
#define SZ_Y    (NB * NK * NL * NCH)            // 3538944

#define RA 3536   // union floats: P1 WL(44*52)+XS(24*52)=3536; prep ut0 16*193=3088;
                  // prep xT 48*49=2352; merge quarter 12*193=2316

struct Smem {
    alignas(16) float RegA[RA];
    alignas(16) float DT[CLEN * NR];
    alignas(16) float BL[CLEN * NN];
    alignas(16) float CL[CLEN * NN];
};
// total: 3536+288+384+384 = 4592 floats = 17.9 KB -> >=3 blocks/CU under any accounting

__device__ __forceinline__ int u_row(int k, int l) {
    int pos = (k >= 2) ? (NL - 1 - l) : l;
    if (k & 1) pos = (pos % 48) * 48 + (pos / 48);
    return pos;
}

// ============== P0: xT (blocks 0..383) + ut0 16-l tiles (blocks 384..671)
__device__ void phase_prep(Smem& sm, const float* __restrict__ x,
                           float* __restrict__ xT, float* __restrict__ ut0) {
    int bid = blockIdx.x, tid = threadIdx.x;
    if (bid < NB * NCH) {
        const float* src = x + (size_t)bid * NL;
        float* dst = xT + (size_t)bid * NL;
        for (int i = tid; i < NL; i += BLK) {
            int h = i / NW, w = i % NW;
            sm.RegA[w * 49 + h] = src[i];
        }
        __syncthreads();
        for (int i = tid; i < NL; i += BLK) {
            dst[i] = sm.RegA[i + i / NH];
        }
    } else if (bid < NB * NCH + 288) {
        int t = bid - NB * NCH;                // 0..287
        int tb = t / 144, lt = t % 144;
        int l0 = lt * 16;
        const float* bx0 = x + (size_t)tb * NCH * NL;
        for (int i = tid; i < NCH * 16; i += BLK) {
            int c = i >> 4, j = i & 15;        // coalesced read along l
            sm.RegA[j * 193 + c] = bx0[(size_t)c * NL + l0 + j];
        }
        __syncthreads();
        float* bo = ut0 + (size_t)tb * NL * NCH;
        for (int i = tid; i < NCH * 16; i += BLK) {
            int j = i / NCH, c = i % NCH;      // coalesced write along c
            bo[(size_t)(l0 + j) * NCH + c] = sm.RegA[j * 193 + c];
        }
    }
}

// ============== P1: proj GEMM + delta + chunk-local scan (standalone)
__device__ void phase_proj(Smem& sm, const float* __restrict__ x,
                           const float* __restrict__ xT,
                           const float* __restrict__ xpw,
                           const float* __restrict__ dtw,
                           const float* __restrict__ dtb,
                           const float* __restrict__ A_logs,
                           const float* __restrict__ Ds,
                           const float* __restrict__ ut0,
                           float* __restrict__ Cbuf,
                           float* __restrict__ cumS,
                           float* __restrict__ ybuf,
                           float* __restrict__ Hend) {
    int bid = blockIdx.x, tid = threadIdx.x;
    int bk = bid / NCHUNK, chk = bid % NCHUNK;
    int lt0 = chk * CLEN;
    int b = bk >> 2, k = bk & 3;
    float* WL = sm.RegA;                       // [44][52]
    float* XS = sm.RegA + 2288;                // [24][52]
    const float* bx = ((k & 1) ? xT : x) + (size_t)b * NCH * NL;
    bool rev = (k >= 2);
    int lt = tid / ND;                         // 0..3 for tid<176
    int dt = tid % ND;
    float acc[6] = {0.f, 0.f, 0.f, 0.f, 0.f, 0.f};
    for (int ph = 0; ph < 4; ++ph) {
        int c0 = ph * 48;
        __syncthreads();
        for (int i = tid; i < ND * 48; i += BLK) {
            int d = i / 48, cc = i % 48;
            WL[d * 52 + cc] = xpw[((size_t)k * ND + d) * NCH + c0 + cc];
        }
        for (int i = tid; i < 48 * CLEN; i += BLK) {
            int cc = i / CLEN, j = i % CLEN;
            int gl = lt0 + j;
            if (rev) gl = NL - 1 - gl;
            XS[j * 52 + cc] = bx[(size_t)(c0 + cc) * NL + gl];
        }
        __syncthreads();
        if (tid < 4 * ND) {
#pragma unroll 4
            for (int g = 0; g < 12; ++g) {
                float4 wv = *(const float4*)&WL[dt * 52 + g * 4];
#pragma unroll
                for (int li = 0; li < 6; ++li) {
                    float4 xv = *(const float4*)&XS[(lt * 6 + li) * 52 + g * 4];
                    acc[li] = fmaf(xv.x, wv.x, acc[li]);
                    acc[li] = fmaf(xv.y, wv.y, acc[li]);
                    acc[li] = fmaf(xv.z, wv.z, acc[li]);
                    acc[li] = fmaf(xv.w, wv.w, acc[li]);
                }
            }
        }
    }
    __syncthreads();
    if (tid < 4 * ND) {
#pragma unroll
        for (int li = 0; li < 6; ++li) {
            int l = lt * 6 + li;
            if (dt < NR) sm.DT[l * NR + dt] = acc[li];
            else if (dt < NR + NN) sm.BL[l * NN + (dt - NR)] = acc[li];
            else {
                sm.CL[l * NN + (dt - NR - NN)] = acc[li];
                Cbuf[((size_t)bk * NL + lt0 + l) * NN + (dt - NR - NN)] = acc[li];
            }
        }
    }
    __syncthreads();
    if (tid < NCH) {
        int c = tid;
        float A2[NN];
        {
            const float4* ap = (const float4*)(A_logs + ((size_t)(k * NCH + c)) * NN);
            float4 a0 = ap[0], a1 = ap[1], a2 = ap[2], a3 = ap[3];
            float t16[16] = {a0.x, a0.y, a0.z, a0.w, a1.x, a1.y, a1.z, a1.w,
                             a2.x, a2.y, a2.z, a2.w, a3.x, a3.y, a3.z, a3.w};
#pragma unroll
            for (int n = 0; n < NN; ++n) A2[n] = -expf(t16[n]) * 1.44269504f;
        }
        const float4* wp = (const float4*)(dtw + ((size_t)k * NCH + c) * NR);
        float4 w0 = wp[0], w1 = wp[1], w2 = wp[2];
        float bias = dtb[k * NCH + c];
        float dval = Ds[k * NCH + c];
        const float* up = ut0 + (size_t)b * NL * NCH + c;
        float* csp = cumS + (size_t)bk * NL * NCH + c;
        float sp[CLEN], uvv[CLEN];
        float S = 0.0f;
#pragma unroll
        for (int i = 0; i < CLEN; ++i) {
            float4 a0 = *(const float4*)&sm.DT[i * NR + 0];
            float4 a1 = *(const float4*)&sm.DT[i * NR + 4];
            float4 a2 = *(const float4*)&sm.DT[i * NR + 8];
            float p0 = fmaf(w0.x, a0.x, fmaf(w0.y, a0.y, bias));
            float p1 = fmaf(w0.z, a0.z, w0.w * a0.w);
            float p2 = fmaf(w1.x, a1.x, fmaf(w1.y, a1.y, w1.z * a1.z));
            float p3 = fmaf(w1.w, a1.w, fmaf(w2.x, a2.x, w2.y * a2.y));
            float p4 = fmaf(w2.z, a2.z, w2.w * a2.w);
            float acc2 = (p0 + p1) + (p2 + p3) + p4;
            float s = fmaxf(acc2, 0.0f) + log1pf(expf(-fabsf(acc2)));
            sp[i] = s;
            S += s;
            csp[(size_t)(lt0 + i) * NCH] = S;          // inclusive cumsum
            uvv[i] = up[(size_t)u_row(k, lt0 + i) * NCH];
        }
        float h[NN];
#pragma unroll
        for (int n = 0; n < NN; ++n) h[n] = 0.0f;
        float* yp = ybuf + ((size_t)bk * NL + lt0) * NCH + c;
#pragma unroll 4
        for (int i = 0; i < CLEN; ++i) {
            float du = sp[i] * uvv[i];
            const float4* br = (const float4*)&sm.BL[i * NN];
            float4 b0 = br[0], b1 = br[1], b2 = br[2], b3 = br[3];
            float Bv[16] = {b0.x, b0.y, b0.z, b0.w, b1.x, b1.y, b1.z, b1.w,
                            b2.x, b2.y, b2.z, b2.w, b3.x, b3.y, b3.z, b3.w};
            const float4* cr = (const float4*)&sm.CL[i * NN];
            float4 c0 = cr[0], c1 = cr[1], c2 = cr[2], c3 = cr[3];
            float Cv[16] = {c0.x, c0.y, c0.z, c0.w, c1.x, c1.y, c1.z, c1.w,
                            c2.x, c2.y, c2.z, c2.w, c3.x, c3.y, c3.z, c3.w};
            float y = 0.0f;
#pragma unroll
            for (int n = 0; n < NN; ++n) {
                float dA = exp2f(sp[i] * A2[n]);
                h[n] = fmaf(dA, h[n], du * Bv[n]);
                y = fmaf(h[n], Cv[n], y);
            }
            y = fmaf(dval, uvv[i], y);
            yp[(size_t)i * NCH] = y;
        }
        size_t ob = (((size_t)bk * NCHUNK + chk) * NCH + c) * NN;
#pragma unroll
        for (int q = 0; q < 4; ++q)
            *(float4*)&Hend[ob + q * 4] =
                make_float4(h[q*4], h[q*4+1], h[q*4+2], h[q*4+3]);
    }
}

// ============== P2: cross-chunk prefix in place (blocks 0..95)
__device__ void phase_s2(const float* __restrict__ cumS,
                         const float* __restrict__ A_logs,
                         float* __restrict__ Hend) {
    int bid = blockIdx.x, tid = threadIdx.x;
    if (bid >= 96) return;
    int g = bid * BLK + tid;                   // 0..24575
    int pbk = g / (NCH * NN);
    int cn = g % (NCH * NN);
    int c = cn / NN, n = cn % NN;
    int pk = pbk & 3;
    float A2 = -expf(A_logs[((size_t)(pk * NCH + c)) * NN + n]) * 1.44269504f;
    float h = 0.0f;
    const float* csp = cumS + (size_t)pbk * NL * NCH + c;
    for (int j = 0; j < NCHUNK; ++j) {
        float S = csp[(size_t)(j * CLEN + CLEN - 1) * NCH];
        size_t idx = (((size_t)pbk * NCHUNK + j) * NCH + c) * NN + n;
        float E = Hend[idx];
        float P = exp2f(S * A2);
        Hend[idx] = h;
        h = fmaf(P, h, E);
    }
}

// ============== P3: y += C · (exp2(cumS·A2) ∘ h_in)   (all 768 blocks)
__device__ void phase_fix(const float* __restrict__ Cbuf,
                          const float* __restrict__ cumS,
                          const float* __restrict__ Hin,
                          const float* __restrict__ A_logs,
                          float* __restrict__ ybuf) {
    int bid = blockIdx.x, tid = threadIdx.x;
    if (tid >= NCH) return;
    int bk = bid / NCHUNK, chk = bid % NCHUNK;
    int lt0 = chk * CLEN;
    int k = bk & 3;
    int c = tid;
    float A2[NN];
    {
        const float4* ap = (const float4*)(A_logs + ((size_t)(k * NCH + c)) * NN);
        float4 a0 = ap[0], a1 = ap[1], a2 = ap[2], a3 = ap[3];
        float t16[16] = {a0.x, a0.y, a0.z, a0.w, a1.x, a1.y, a1.z, a1.w,
                         a2.x, a2.y, a2.z, a2.w, a3.x, a3.y, a3.z, a3.w};
#pragma unroll
        for (int n = 0; n < NN; ++n) A2[n] = -expf(t16[n]) * 1.44269504f;
    }
    float hin[NN];
    {
        size_t ob = (((size_t)bk * NCHUNK + chk) * NCH + c) * NN;
        const float4* hp = (const float4*)(Hin + ob);
        float4 h0 = hp[0], h1 = hp[1], h2 = hp[2], h3 = hp[3];
        float t16[16] = {h0.x, h0.y, h0.z, h0.w, h1.x, h1.y, h1.z, h1.w,
                         h2.x, h2.y, h2.z, h2.w, h3.x, h3.y, h3.z, h3.w};
#pragma unroll
        for (int n = 0; n < NN; ++n) hin[n] = t16[n];
    }
    const float* csp = cumS + (size_t)bk * NL * NCH + c;
    float* yp = ybuf + (size_t)bk * NL * NCH + c;
#pragma unroll 4
    for (int i = 0; i < CLEN; ++i) {
        int l = lt0 + i;
        float cs = csp[(size_t)l * NCH];
        const float4* cr = (const float4*)(Cbuf + ((size_t)bk * NL + l) * NN);
        float4 c0 = cr[0], c1 = cr[1], c2 = cr[2], c3 = cr[3];
        float Cv[16] = {c0.x, c0.y, c0.z, c0.w, c1.x, c1.y, c1.z, c1.w,
                        c2.x, c2.y, c2.z, c2.w, c3.x, c3.y, c3.z, c3.w};
        float corr = 0.0f;
#pragma unroll
        for (int n = 0; n < NN; ++n) {
            float e = exp2f(cs * A2[n]);
            corr = fmaf(Cv[n] * hin[n], e, corr);
        }
        yp[(size_t)l * NCH] += corr;
    }
}

// ============== P4: cross-merge, quarter tiles (blocks 0..95)
__device__ void phase_merge(Smem& sm, const float* __restrict__ ybuf,
                            float* __restrict__ out) {
    int bid = blockIdx.x, tid = threadIdx.x;
    if (bid >= NB * NH) return;
    int mb = bid / NH;
    int hh = bid % NH;
    const float* Y0 = ybuf + (size_t)(mb * NK + 0) * NL * NCH;
    const float* Y1 = ybuf + (size_t)(mb * NK + 1) * NL * NCH;
    const float* Y2 = ybuf + (size_t)(mb * NK + 2) * NL * NCH;
    const float* Y3 = ybuf + (size_t)(mb * NK + 3) * NL * NCH;
    for (int q = 0; q < 4; ++q) {
        __syncthreads();
        for (int i = tid; i < 12 * NCH; i += BLK) {
            int wq = i / NCH, c = i % NCH;
            int w = q * 12 + wq;
            int hw = hh * NW + w;
            int wh = w * NH + hh;
            sm.RegA[wq * 193 + c] = Y0[(size_t)hw * NCH + c]
                                  + Y2[(size_t)(NL - 1 - hw) * NCH + c]
                                  + Y1[(size_t)wh * NCH + c]
                                  + Y3[(size_t)(NL - 1 - wh) * NCH + c];
        }
        __syncthreads();
        for (int i = tid; i < NCH * 12; i += BLK) {
            int c = i / 12, wq = i % 12;
            out[((size_t)(mb * NCH + c)) * NL + hh * NW + q * 12 + wq] =
                sm.RegA[wq * 193 + c];
        }
    }
}

// ================= cooperative mega-kernel =================
__global__ __launch_bounds__(BLK, 3) void k_mega(const float* __restrict__ x,
                                                 const float* __restrict__ xpw,
                                                 const float* __restrict__ dtw,
                                                 const float* __restrict__ A_logs,
                                                 const float* __restrict__ Ds,
                                                 const float* __restrict__ dtb,
                                                 float* __restrict__ xT,
                                                 float* __restrict__ ut0,
                                                 float* __restrict__ Cbuf,
                                                 float* __restrict__ cumS,
                                                 float* __restrict__ ybuf,
                                                 float* __restrict__ Hend,
                                                 float* __restrict__ out) {
    cg::grid_group gg = cg::this_grid();
    __shared__ Smem sm;
    phase_prep(sm, x, xT, ut0);
    gg.sync();
    phase_proj(sm, x, xT, xpw, dtw, dtb, A_logs, Ds, ut0, Cbuf, cumS, ybuf, Hend);
    gg.sync();
    phase_s2(cumS, A_logs, Hend);
    gg.sync();
    phase_fix(Cbuf, cumS, Hend, A_logs, ybuf);
    gg.sync();
    phase_merge(sm, ybuf, out);
}

// ================= standalone fallback kernels =================
__global__ __launch_bounds__(BLK, 3) void k_f0(const float* x, float* xT, float* ut0) {
    __shared__ Smem sm;
    phase_prep(sm, x, xT, ut0);
}
__global__ __launch_bounds__(BLK, 3) void k_f1(const float* x, const float* xT,
                                               const float* xpw, const float* dtw,
                                               const float* dtb, const float* A_logs,
                                               const float* Ds, const float* ut0,
                                               float* Cbuf, float* cumS,
                                               float* ybuf, float* Hend) {
    __shared__ Smem sm;
    phase_proj(sm, x, xT, xpw, dtw, dtb, A_logs, Ds, ut0, Cbuf, cumS, ybuf, Hend);
}
__global__ __launch_bounds__(BLK, 3) void k_f2(const float* cumS, const float* A_logs,
                                               float* Hend) {
    phase_s2(cumS, A_logs, Hend);
}
__global__ __launch_bounds__(BLK, 3) void k_f3(const float* Cbuf, const float* cumS,
                                               const float* Hin, const float* A_logs,
                                               float* ybuf) {
    phase_fix(Cbuf, cumS, Hin, A_logs, ybuf);
}
__global__ __launch_bounds__(BLK, 3) void k_f4(const float* ybuf, float* out) {
    __shared__ Smem sm;
    phase_merge(sm, ybuf, out);
}

extern "C" void kernel_launch(void* const* d_in, const int* in_sizes, int n_in,
                              void* d_out, int out_size, void* d_ws, size_t ws_size,
                              hipStream_t stream) {
    const float* x      = (const float*)d_in[0];
    const float* xpw    = (const float*)d_in[1];
    const float* dtw    = (const float*)d_in[2];
    const float* A_logs = (const float*)d_in[3];
    const float* Ds     = (const float*)d_in[4];
    const float* dtb    = (const float*)d_in[5];
    float* out = (float*)d_out;

    float* ws = (float*)d_ws;
    float* xT   = ws;
    float* ut0  = xT + SZ_XT;
    float* Cbuf = ut0 + SZ_UT0;
    float* cumS = Cbuf + SZ_CB;
    float* ybuf = cumS + SZ_CUMS;
    float* Hend = ybuf + SZ_Y;     // P2 rewrites in place to Hin

    void* args[] = {&x, &xpw, &dtw, &A_logs, &Ds, &dtb,
                    &xT, &ut0, &Cbuf, &cumS, &ybuf, &Hend, &out};
    hipError_t e = hipLaunchCooperativeKernel((void*)k_mega, dim3(GRID), dim3(BLK),
                                              args, 0, stream);
    if (e != hipSuccess) {
        // deterministic fallback: same phases as separate kernels
        (void)hipGetLastError();
        k_f0<<<NB * NCH + 288, BLK, 0, stream>>>(x, xT, ut0);
        k_f1<<<GRID, BLK, 0, stream>>>(x, xT, xpw, dtw, dtb, A_logs, Ds, ut0,
                                       Cbuf, cumS, ybuf, Hend);
        k_f2<<<96, BLK, 0, stream>>>(cumS, A_logs, Hend);
        k_f3<<<GRID, BLK, 0, stream>>>(Cbuf, cumS, Hend, A_logs, ybuf);
        k_f4<<<96, BLK, 0, stream>>>(ybuf, out);
    }
}

// Round 10
// 196.704 us; speedup vs baseline: 2.9497x; 2.9497x over previous
//
#include <hip/hip_runtime.h>
#include <math.h>

#define NB 2
#define NCH 192
#define NH 48
#define NW 48
#define NL 2304
#define NK 4
#define NN 16
#define NR 12
#define ND 44
#define CLEN 16
#define NCHUNK 144                  // NL / CLEN
#define GRID1 (NB * NK * NCHUNK)    // 1152
#define BLK 256

// workspace float sizes
#define SZ_CB   (NB * NK * NL * NN)             // 294912
#define SZ_CUMS (NB * NK * NL * NCH)            // 3538944
#define SZ_Y    (NB * NK * NL * NCH)            // 3538944
#define SZ_HEND (NB * NK * NCHUNK * NCH * NN)   // 3538944

// ============ K1: proj GEMM + delta + chunk-local scan (no prep needed)
// Outputs: Cbuf[bk][l][16], cumS[bk][l][c] (inclusive), ybuf[bk][l][c] = y_local,
//          Hend[bk][chk][c][16]
__global__ __launch_bounds__(BLK, 4) void k_projscan(const float* __restrict__ x,
                                                     const float* __restrict__ xpw,
                                                     const float* __restrict__ dtw,
                                                     const float* __restrict__ dtb,
                                                     const float* __restrict__ A_logs,
                                                     const float* __restrict__ Ds,
                                                     float* __restrict__ Cbuf,
                                                     float* __restrict__ cumS,
                                                     float* __restrict__ ybuf,
                                                     float* __restrict__ Hend) {
    int bid = blockIdx.x, tid = threadIdx.x;
    int bk = bid / NCHUNK, chk = bid % NCHUNK;
    int lt0 = chk * CLEN;
    int b = bk >> 2, k = bk & 3;
    int lt = tid / ND;                         // 0..3 (l-group of 4) for tid<176
    int dt = tid % ND;                         // 0..43
    __shared__ float WL[ND * 52];              // [d][cc]  9.2 KB
    __shared__ float XS[CLEN * 52];            // [j][cc]  3.3 KB
    __shared__ float DT[CLEN * NR];
    __shared__ float BL[CLEN * NN];
    __shared__ float CL[CLEN * NN];            // total 14.9 KB
    const float* bx = x + (size_t)b * NCH * NL;
    bool rev = (k >= 2), tr = (k & 1);
    float acc[4] = {0.f, 0.f, 0.f, 0.f};
    float uvv[CLEN];                           // u captured from XS, lives in regs
    int c = tid;                               // tail channel identity (c < 192)
    int myph = c / 48, mycc = c % 48;
    for (int ph = 0; ph < 4; ++ph) {
        int c0 = ph * 48;
        __syncthreads();
        for (int i = tid; i < ND * 48; i += BLK) {
            int d = i / 48, cc = i % 48;
            WL[d * 52 + cc] = xpw[((size_t)k * ND + d) * NCH + c0 + cc];
        }
        for (int i = tid; i < 48 * CLEN; i += BLK) {
            int cc = i / CLEN, j = i % CLEN;
            int gl = rev ? (NL - 1 - lt0 - j) : (lt0 + j);
            int pos = tr ? ((gl % 48) * 48 + gl / 48) : gl;  // w const per chunk
            XS[j * 52 + cc] = bx[(size_t)(c0 + cc) * NL + pos];
        }
        __syncthreads();
        if (tid < 4 * ND) {
#pragma unroll 4
            for (int g = 0; g < 12; ++g) {
                float4 wv = *(const float4*)&WL[dt * 52 + g * 4];
#pragma unroll
                for (int li = 0; li < 4; ++li) {
                    float4 xv = *(const float4*)&XS[(lt * 4 + li) * 52 + g * 4];
                    acc[li] = fmaf(xv.x, wv.x, acc[li]);
                    acc[li] = fmaf(xv.y, wv.y, acc[li]);
                    acc[li] = fmaf(xv.z, wv.z, acc[li]);
                    acc[li] = fmaf(xv.w, wv.w, acc[li]);
                }
            }
        }
        // capture u for the tail: XS holds xs[k] for channels [c0,c0+48)
        if (ph == myph && c < NCH) {
#pragma unroll
            for (int i = 0; i < CLEN; ++i) uvv[i] = XS[i * 52 + mycc];
        }
    }
    __syncthreads();
    if (tid < 4 * ND) {
#pragma unroll
        for (int li = 0; li < 4; ++li) {
            int l = lt * 4 + li;
            if (dt < NR) DT[l * NR + dt] = acc[li];
            else if (dt < NR + NN) BL[l * NN + (dt - NR)] = acc[li];
            else {
                CL[l * NN + (dt - NR - NN)] = acc[li];
                Cbuf[((size_t)bk * NL + lt0 + l) * NN + (dt - NR - NN)] = acc[li];
            }
        }
    }
    __syncthreads();
    if (tid < NCH) {
        float A2[NN];
        {
            const float4* ap = (const float4*)(A_logs + ((size_t)(k * NCH + c)) * NN);
            float4 a0 = ap[0], a1 = ap[1], a2 = ap[2], a3 = ap[3];
            float t16[16] = {a0.x, a0.y, a0.z, a0.w, a1.x, a1.y, a1.z, a1.w,
                             a2.x, a2.y, a2.z, a2.w, a3.x, a3.y, a3.z, a3.w};
#pragma unroll
            for (int n = 0; n < NN; ++n) A2[n] = -expf(t16[n]) * 1.44269504f;
        }
        const float4* wp = (const float4*)(dtw + ((size_t)k * NCH + c) * NR);
        float4 w0 = wp[0], w1 = wp[1], w2 = wp[2];
        float bias = dtb[k * NCH + c];
        float dval = Ds[k * NCH + c];
        float* csp = cumS + (size_t)bk * NL * NCH + c;
        float sp[CLEN];
        float S = 0.0f;
#pragma unroll
        for (int i = 0; i < CLEN; ++i) {
            float4 a0 = *(const float4*)&DT[i * NR + 0];
            float4 a1 = *(const float4*)&DT[i * NR + 4];
            float4 a2 = *(const float4*)&DT[i * NR + 8];
            float p0 = fmaf(w0.x, a0.x, fmaf(w0.y, a0.y, bias));
            float p1 = fmaf(w0.z, a0.z, w0.w * a0.w);
            float p2 = fmaf(w1.x, a1.x, fmaf(w1.y, a1.y, w1.z * a1.z));
            float p3 = fmaf(w1.w, a1.w, fmaf(w2.x, a2.x, w2.y * a2.y));
            float p4 = fmaf(w2.z, a2.z, w2.w * a2.w);
            float acc2 = (p0 + p1) + (p2 + p3) + p4;
            float s = fmaxf(acc2, 0.0f) + log1pf(expf(-fabsf(acc2)));
            sp[i] = s;
            S += s;
            csp[(size_t)(lt0 + i) * NCH] = S;
        }
        float h[NN];
#pragma unroll
        for (int n = 0; n < NN; ++n) h[n] = 0.0f;
        float* yp = ybuf + ((size_t)bk * NL + lt0) * NCH + c;
#pragma unroll 4
        for (int i = 0; i < CLEN; ++i) {
            float du = sp[i] * uvv[i];
            const float4* br = (const float4*)&BL[i * NN];
            float4 b0 = br[0], b1 = br[1], b2 = br[2], b3 = br[3];
            float Bv[16] = {b0.x, b0.y, b0.z, b0.w, b1.x, b1.y, b1.z, b1.w,
                            b2.x, b2.y, b2.z, b2.w, b3.x, b3.y, b3.z, b3.w};
            const float4* cr = (const float4*)&CL[i * NN];
            float4 c0v = cr[0], c1 = cr[1], c2 = cr[2], c3 = cr[3];
            float Cv[16] = {c0v.x, c0v.y, c0v.z, c0v.w, c1.x, c1.y, c1.z, c1.w,
                            c2.x, c2.y, c2.z, c2.w, c3.x, c3.y, c3.z, c3.w};
            float y = 0.0f;
#pragma unroll
            for (int n = 0; n < NN; ++n) {
                float dA = exp2f(sp[i] * A2[n]);
                h[n] = fmaf(dA, h[n], du * Bv[n]);
                y = fmaf(h[n], Cv[n], y);
            }
            y = fmaf(dval, uvv[i], y);
            yp[(size_t)i * NCH] = y;
        }
        size_t ob = (((size_t)bk * NCHUNK + chk) * NCH + c) * NN;
#pragma unroll
        for (int q = 0; q < 4; ++q)
            *(float4*)&Hend[ob + q * 4] =
                make_float4(h[q*4], h[q*4+1], h[q*4+2], h[q*4+3]);
    }
}

// ============ K2: cross-chunk prefix in place (Hend -> Hin), 96 blocks
__global__ __launch_bounds__(BLK) void k_s2(const float* __restrict__ cumS,
                                            const float* __restrict__ A_logs,
                                            float* __restrict__ Hend) {
    int g = blockIdx.x * BLK + threadIdx.x;    // 0..24575
    int bk = g / (NCH * NN);
    int cn = g % (NCH * NN);
    int c = cn / NN, n = cn % NN;
    int k = bk & 3;
    float A2 = -expf(A_logs[((size_t)(k * NCH + c)) * NN + n]) * 1.44269504f;
    float h = 0.0f;
    const float* csp = cumS + (size_t)bk * NL * NCH + c;
    for (int j = 0; j < NCHUNK; ++j) {
        float S = csp[(size_t)(j * CLEN + CLEN - 1) * NCH];
        size_t idx = (((size_t)bk * NCHUNK + j) * NCH + c) * NN + n;
        float E = Hend[idx];
        float P = exp2f(S * A2);
        Hend[idx] = h;
        h = fmaf(P, h, E);
    }
}

// ============ K3: y += C · (exp2(cumS·A2) ∘ h_in), 1152 blocks, no syncs
__global__ __launch_bounds__(BLK) void k_fix(const float* __restrict__ Cbuf,
                                             const float* __restrict__ cumS,
                                             const float* __restrict__ Hin,
                                             const float* __restrict__ A_logs,
                                             float* __restrict__ ybuf) {
    int bid = blockIdx.x, tid = threadIdx.x;
    if (tid >= NCH) return;
    int bk = bid / NCHUNK, chk = bid % NCHUNK;
    int lt0 = chk * CLEN;
    int k = bk & 3;
    int c = tid;
    float A2[NN];
    {
        const float4* ap = (const float4*)(A_logs + ((size_t)(k * NCH + c)) * NN);
        float4 a0 = ap[0], a1 = ap[1], a2 = ap[2], a3 = ap[3];
        float t16[16] = {a0.x, a0.y, a0.z, a0.w, a1.x, a1.y, a1.z, a1.w,
                         a2.x, a2.y, a2.z, a2.w, a3.x, a3.y, a3.z, a3.w};
#pragma unroll
        for (int n = 0; n < NN; ++n) A2[n] = -expf(t16[n]) * 1.44269504f;
    }
    float hin[NN];
    {
        size_t ob = (((size_t)bk * NCHUNK + chk) * NCH + c) * NN;
        const float4* hp = (const float4*)(Hin + ob);
        float4 h0 = hp[0], h1 = hp[1], h2 = hp[2], h3 = hp[3];
        float t16[16] = {h0.x, h0.y, h0.z, h0.w, h1.x, h1.y, h1.z, h1.w,
                         h2.x, h2.y, h2.z, h2.w, h3.x, h3.y, h3.z, h3.w};
#pragma unroll
        for (int n = 0; n < NN; ++n) hin[n] = t16[n];
    }
    const float* csp = cumS + (size_t)bk * NL * NCH + c;
    float* yp = ybuf + (size_t)bk * NL * NCH + c;
#pragma unroll 4
    for (int i = 0; i < CLEN; ++i) {
        int l = lt0 + i;
        float cs = csp[(size_t)l * NCH];
        const float4* cr = (const float4*)(Cbuf + ((size_t)bk * NL + l) * NN);
        float4 c0 = cr[0], c1 = cr[1], c2 = cr[2], c3 = cr[3];
        float Cv[16] = {c0.x, c0.y, c0.z, c0.w, c1.x, c1.y, c1.z, c1.w,
                        c2.x, c2.y, c2.z, c2.w, c3.x, c3.y, c3.z, c3.w};
        float corr = 0.0f;
#pragma unroll
        for (int n = 0; n < NN; ++n) {
            float e = exp2f(cs * A2[n]);
            corr = fmaf(Cv[n] * hin[n], e, corr);
        }
        yp[(size_t)l * NCH] += corr;
    }
}

// ============ K4: cross-merge from [bk][l][c], 96 blocks
__global__ __launch_bounds__(BLK) void k_merge(const float* __restrict__ ybuf,
                                               float* __restrict__ out) {
    int b = blockIdx.x / NH;
    int hh = blockIdx.x % NH;
    __shared__ float tile[NW * 193];
    const float* Y0 = ybuf + (size_t)(b * NK + 0) * NL * NCH;
    const float* Y1 = ybuf + (size_t)(b * NK + 1) * NL * NCH;
    const float* Y2 = ybuf + (size_t)(b * NK + 2) * NL * NCH;
    const float* Y3 = ybuf + (size_t)(b * NK + 3) * NL * NCH;
    for (int i = threadIdx.x; i < NW * NCH; i += BLK) {
        int w = i / NCH, c = i % NCH;
        int hw = hh * NW + w;
        int wh = w * NH + hh;
        float v = Y0[(size_t)hw * NCH + c]
                + Y2[(size_t)(NL - 1 - hw) * NCH + c]
                + Y1[(size_t)wh * NCH + c]
                + Y3[(size_t)(NL - 1 - wh) * NCH + c];
        tile[w * 193 + c] = v;
    }
    __syncthreads();
    for (int i = threadIdx.x; i < NW * NCH; i += BLK) {
        int c = i / NW, w = i % NW;
        out[((size_t)(b * NCH + c)) * NL + hh * NW + w] = tile[w * 193 + c];
    }
}

extern "C" void kernel_launch(void* const* d_in, const int* in_sizes, int n_in,
                              void* d_out, int out_size, void* d_ws, size_t ws_size,
                              hipStream_t stream) {
    const float* x      = (const float*)d_in[0];
    const float* xpw    = (const float*)d_in[1];
    const float* dtw    = (const float*)d_in[2];
    const float* A_logs = (const float*)d_in[3];
    const float* Ds     = (const float*)d_in[4];
    const float* dtb    = (const float*)d_in[5];
    float* out = (float*)d_out;

    float* ws = (float*)d_ws;
    float* Cbuf = ws;
    float* cumS = Cbuf + SZ_CB;
    float* ybuf = cumS + SZ_CUMS;
    float* Hend = ybuf + SZ_Y;     // k_s2 rewrites in place to Hin

    k_projscan<<<GRID1, BLK, 0, stream>>>(x, xpw, dtw, dtb, A_logs, Ds,
                                          Cbuf, cumS, ybuf, Hend);
    k_s2<<<96, BLK, 0, stream>>>(cumS, A_logs, Hend);
    k_fix<<<GRID1, BLK, 0, stream>>>(Cbuf, cumS, Hend, A_logs, ybuf);
    k_merge<<<NB * NH, BLK, 0, stream>>>(ybuf, out);
}

// Round 11
// 195.486 us; speedup vs baseline: 2.9681x; 1.0062x over previous
//
#include <hip/hip_runtime.h>
#include <math.h>

#define NB 2
#define NCH 192
#define NH 48
#define NW 48
#define NL 2304
#define NK 4
#define NN 16
#define NR 12
#define ND 44
#define CLEN 16
#define NCHUNK 144                  // NL / CLEN
#define GRID1 (NB * NK * NCHUNK)    // 1152
#define BLK1 192

// workspace float sizes
#define SZ_CB   (NB * NK * NL * NN)             // 294912
#define SZ_CUMS (NB * NK * NL * NCH)            // 3538944
#define SZ_Y    (NB * NK * NL * NCH)            // 3538944
#define SZ_HEND (NB * NK * NCHUNK * NCH * NN)   // 3538944

// ============ K1: proj GEMM + delta + chunk-local scan (prep-free)
// Outputs: Cbuf[bk][l][16], cumS[bk][l][c] (inclusive), ybuf[bk][l][c] = y_local,
//          Hend[bk][chk][c][16]
__global__ __launch_bounds__(BLK1) void k_projscan(const float* __restrict__ x,
                                                   const float* __restrict__ xpw,
                                                   const float* __restrict__ dtw,
                                                   const float* __restrict__ dtb,
                                                   const float* __restrict__ A_logs,
                                                   const float* __restrict__ Ds,
                                                   float* __restrict__ Cbuf,
                                                   float* __restrict__ cumS,
                                                   float* __restrict__ ybuf,
                                                   float* __restrict__ Hend) {
    int bid = blockIdx.x, tid = threadIdx.x;
    int bk = bid / NCHUNK, chk = bid % NCHUNK;
    int lt0 = chk * CLEN;
    int b = bk >> 2, k = bk & 3;
    int lt = tid / ND;                         // 0..3 (l-group of 4) for tid<176
    int dt = tid % ND;                         // 0..43
    __shared__ float WL[96 * 45];              // [cc][d]  17.3 KB
    __shared__ float XS[96 * CLEN];            // [cc][l]   6.1 KB
    __shared__ float DT[CLEN * NR];
    __shared__ float BL[CLEN * NN];
    __shared__ float CL[CLEN * NN];            // total 25.6 KB
    const float* bx = x + (size_t)b * NCH * NL;
    bool rev = (k >= 2), tr = (k & 1);
    float acc[4] = {0.f, 0.f, 0.f, 0.f};
    float uvv[CLEN];                           // u captured from XS
    int c = tid;                               // tail channel identity
    int myph = c / 96, mycc = c % 96;
    for (int ph = 0; ph < 2; ++ph) {
        int c0 = ph * 96;
        __syncthreads();
        // stage W: [cc][45], coalesced global along cc, LDS stride 45 (2-way max)
        for (int i = tid; i < ND * 96; i += BLK1) {
            int d = i / 96, cc = i % 96;
            WL[cc * 45 + d] = xpw[((size_t)k * ND + d) * NCH + c0 + cc];
        }
        // stage X: [cc][16], lanes vary j fast (coalesced / stride-48 L2 runs)
        for (int i = tid; i < 96 * CLEN; i += BLK1) {
            int cc = i >> 4, j = i & 15;
            int gl = rev ? (NL - 1 - lt0 - j) : (lt0 + j);
            int pos = tr ? ((gl % 48) * 48 + gl / 48) : gl;
            XS[cc * 16 + j] = bx[(size_t)(c0 + cc) * NL + pos];
        }
        __syncthreads();
        if (tid < 4 * ND) {
#pragma unroll 8
            for (int cc = 0; cc < 96; ++cc) {
                float4 xv = *(const float4*)&XS[cc * 16 + lt * 4];  // broadcast
                float wv = WL[cc * 45 + dt];                        // ≤2-way
                acc[0] = fmaf(xv.x, wv, acc[0]);
                acc[1] = fmaf(xv.y, wv, acc[1]);
                acc[2] = fmaf(xv.z, wv, acc[2]);
                acc[3] = fmaf(xv.w, wv, acc[3]);
            }
        }
        // capture u for the tail (skewed to spread banks: 2-way instead of 32-way)
        if (ph == myph) {
#pragma unroll
            for (int ii = 0; ii < CLEN; ++ii) {
                int i2 = (ii + mycc) & 15;
                uvv[i2] = XS[mycc * 16 + i2];
            }
        }
    }
    __syncthreads();
    if (tid < 4 * ND) {
#pragma unroll
        for (int li = 0; li < 4; ++li) {
            int l = lt * 4 + li;
            if (dt < NR) DT[l * NR + dt] = acc[li];
            else if (dt < NR + NN) BL[l * NN + (dt - NR)] = acc[li];
            else {
                CL[l * NN + (dt - NR - NN)] = acc[li];
                Cbuf[((size_t)bk * NL + lt0 + l) * NN + (dt - NR - NN)] = acc[li];
            }
        }
    }
    __syncthreads();
    {
        float A2[NN];
        {
            const float4* ap = (const float4*)(A_logs + ((size_t)(k * NCH + c)) * NN);
            float4 a0 = ap[0], a1 = ap[1], a2 = ap[2], a3 = ap[3];
            float t16[16] = {a0.x, a0.y, a0.z, a0.w, a1.x, a1.y, a1.z, a1.w,
                             a2.x, a2.y, a2.z, a2.w, a3.x, a3.y, a3.z, a3.w};
#pragma unroll
            for (int n = 0; n < NN; ++n) A2[n] = -expf(t16[n]) * 1.44269504f;
        }
        const float4* wp = (const float4*)(dtw + ((size_t)k * NCH + c) * NR);
        float4 w0 = wp[0], w1 = wp[1], w2 = wp[2];
        float bias = dtb[k * NCH + c];
        float dval = Ds[k * NCH + c];
        float* csp = cumS + (size_t)bk * NL * NCH + c;
        float sp[CLEN];
        float S = 0.0f;
#pragma unroll
        for (int i = 0; i < CLEN; ++i) {
            float4 a0 = *(const float4*)&DT[i * NR + 0];
            float4 a1 = *(const float4*)&DT[i * NR + 4];
            float4 a2 = *(const float4*)&DT[i * NR + 8];
            float p0 = fmaf(w0.x, a0.x, fmaf(w0.y, a0.y, bias));
            float p1 = fmaf(w0.z, a0.z, w0.w * a0.w);
            float p2 = fmaf(w1.x, a1.x, fmaf(w1.y, a1.y, w1.z * a1.z));
            float p3 = fmaf(w1.w, a1.w, fmaf(w2.x, a2.x, w2.y * a2.y));
            float p4 = fmaf(w2.z, a2.z, w2.w * a2.w);
            float acc2 = (p0 + p1) + (p2 + p3) + p4;
            float s = fmaxf(acc2, 0.0f) + log1pf(expf(-fabsf(acc2)));
            sp[i] = s;
            S += s;
            csp[(size_t)(lt0 + i) * NCH] = S;
        }
        float h[NN];
#pragma unroll
        for (int n = 0; n < NN; ++n) h[n] = 0.0f;
        float* yp = ybuf + ((size_t)bk * NL + lt0) * NCH + c;
#pragma unroll 4
        for (int i = 0; i < CLEN; ++i) {
            float du = sp[i] * uvv[i];
            const float4* br = (const float4*)&BL[i * NN];
            float4 b0 = br[0], b1 = br[1], b2 = br[2], b3 = br[3];
            float Bv[16] = {b0.x, b0.y, b0.z, b0.w, b1.x, b1.y, b1.z, b1.w,
                            b2.x, b2.y, b2.z, b2.w, b3.x, b3.y, b3.z, b3.w};
            const float4* cr = (const float4*)&CL[i * NN];
            float4 c0v = cr[0], c1 = cr[1], c2 = cr[2], c3 = cr[3];
            float Cv[16] = {c0v.x, c0v.y, c0v.z, c0v.w, c1.x, c1.y, c1.z, c1.w,
                            c2.x, c2.y, c2.z, c2.w, c3.x, c3.y, c3.z, c3.w};
            float y = 0.0f;
#pragma unroll
            for (int n = 0; n < NN; ++n) {
                float dA = exp2f(sp[i] * A2[n]);
                h[n] = fmaf(dA, h[n], du * Bv[n]);
                y = fmaf(h[n], Cv[n], y);
            }
            y = fmaf(dval, uvv[i], y);
            yp[(size_t)i * NCH] = y;
        }
        size_t ob = (((size_t)bk * NCHUNK + chk) * NCH + c) * NN;
#pragma unroll
        for (int q = 0; q < 4; ++q)
            *(float4*)&Hend[ob + q * 4] =
                make_float4(h[q*4], h[q*4+1], h[q*4+2], h[q*4+3]);
    }
}

// ============ K2: cross-chunk prefix in place (Hend -> Hin), 384 blocks x 64
__global__ __launch_bounds__(64) void k_s2(const float* __restrict__ cumS,
                                           const float* __restrict__ A_logs,
                                           float* __restrict__ Hend) {
    int g = blockIdx.x * 64 + threadIdx.x;     // 0..24575
    int bk = g / (NCH * NN);
    int cn = g % (NCH * NN);
    int c = cn / NN, n = cn % NN;
    int k = bk & 3;
    float A2 = -expf(A_logs[((size_t)(k * NCH + c)) * NN + n]) * 1.44269504f;
    float h = 0.0f;
    const float* csp = cumS + (size_t)bk * NL * NCH + c;
    for (int j = 0; j < NCHUNK; ++j) {
        float S = csp[(size_t)(j * CLEN + CLEN - 1) * NCH];
        size_t idx = (((size_t)bk * NCHUNK + j) * NCH + c) * NN + n;
        float E = Hend[idx];
        float P = exp2f(S * A2);
        Hend[idx] = h;
        h = fmaf(P, h, E);
    }
}

// ============ K3: fused correction + cross-merge, 384 blocks x 192
// out[b][c][s_hw] = Σ over 4 (k, scan-l) pairs of (y_local + C·(exp2(cs·A2)∘hin))
__global__ __launch_bounds__(BLK1) void k_fixmerge(const float* __restrict__ ybuf,
                                                   const float* __restrict__ Cbuf,
                                                   const float* __restrict__ cumS,
                                                   const float* __restrict__ Hin,
                                                   const float* __restrict__ A_logs,
                                                   float* __restrict__ out) {
    int bid = blockIdx.x;
    int mb = bid / 192;
    int rem = bid % 192;
    int hh = rem / 4;
    int q = rem % 4;
    int c = threadIdx.x;                       // 0..191
    float accw[12];
#pragma unroll
    for (int w = 0; w < 12; ++w) accw[w] = 0.0f;
#pragma unroll
    for (int k = 0; k < NK; ++k) {
        int bk = mb * NK + k;
        float A2[NN];
        {
            const float4* ap = (const float4*)(A_logs + ((size_t)(k * NCH + c)) * NN);
            float4 a0 = ap[0], a1 = ap[1], a2 = ap[2], a3 = ap[3];
            float t16[16] = {a0.x, a0.y, a0.z, a0.w, a1.x, a1.y, a1.z, a1.w,
                             a2.x, a2.y, a2.z, a2.w, a3.x, a3.y, a3.z, a3.w};
#pragma unroll
            for (int n = 0; n < NN; ++n) A2[n] = -expf(t16[n]) * 1.44269504f;
        }
        const float* yb = ybuf + (size_t)bk * NL * NCH;
        const float* cs = cumS + (size_t)bk * NL * NCH;
        const float* cb = Cbuf + (size_t)bk * NL * NN;
        const float* hb = Hin + (size_t)bk * NCHUNK * NCH * NN;
        for (int w = 0; w < 12; ++w) {
            int s_hw = hh * NW + q * 12 + w;
            int s_wh = (q * 12 + w) * NH + hh;
            int sp = (k & 1) ? s_wh : s_hw;    // spatial index this direction covers
            int l = (k >= 2) ? (NL - 1 - sp) : sp;   // scan position
            float csv = cs[(size_t)l * NCH + c];
            const float4* cr = (const float4*)(cb + (size_t)l * NN);
            float4 c0 = cr[0], c1 = cr[1], c2 = cr[2], c3 = cr[3];
            float Cv[16] = {c0.x, c0.y, c0.z, c0.w, c1.x, c1.y, c1.z, c1.w,
                            c2.x, c2.y, c2.z, c2.w, c3.x, c3.y, c3.z, c3.w};
            const float4* hp = (const float4*)(hb + (((size_t)(l / CLEN) * NCH + c) * NN));
            float4 h0 = hp[0], h1 = hp[1], h2 = hp[2], h3 = hp[3];
            float hv[16] = {h0.x, h0.y, h0.z, h0.w, h1.x, h1.y, h1.z, h1.w,
                            h2.x, h2.y, h2.z, h2.w, h3.x, h3.y, h3.z, h3.w};
            float v = yb[(size_t)l * NCH + c];
#pragma unroll
            for (int n = 0; n < NN; ++n) {
                float e = exp2f(csv * A2[n]);
                v = fmaf(Cv[n] * hv[n], e, v);
            }
            accw[w] += v;
        }
    }
    float* op = out + ((size_t)(mb * NCH + c)) * NL + hh * NW + q * 12;
#pragma unroll
    for (int w = 0; w < 12; ++w) op[w] = accw[w];
}

extern "C" void kernel_launch(void* const* d_in, const int* in_sizes, int n_in,
                              void* d_out, int out_size, void* d_ws, size_t ws_size,
                              hipStream_t stream) {
    const float* x      = (const float*)d_in[0];
    const float* xpw    = (const float*)d_in[1];
    const float* dtw    = (const float*)d_in[2];
    const float* A_logs = (const float*)d_in[3];
    const float* Ds     = (const float*)d_in[4];
    const float* dtb    = (const float*)d_in[5];
    float* out = (float*)d_out;

    float* ws = (float*)d_ws;
    float* Cbuf = ws;
    float* cumS = Cbuf + SZ_CB;
    float* ybuf = cumS + SZ_CUMS;
    float* Hend = ybuf + SZ_Y;     // k_s2 rewrites in place to Hin

    k_projscan<<<GRID1, BLK1, 0, stream>>>(x, xpw, dtw, dtb, A_logs, Ds,
                                           Cbuf, cumS, ybuf, Hend);
    k_s2<<<384, 64, 0, stream>>>(cumS, A_logs, Hend);
    k_fixmerge<<<384, BLK1, 0, stream>>>(ybuf, Cbuf, cumS, Hend, A_logs, out);
}

// Round 13
// 192.057 us; speedup vs baseline: 3.0211x; 1.0179x over previous
//
#include <hip/hip_runtime.h>
#include <math.h>

#define NB 2
#define NCH 192
#define NH 48
#define NW 48
#define NL 2304
#define NK 4
#define NN 16
#define NR 12
#define ND 44
#define CLEN 16
#define NCHUNK 144                  // NL / CLEN
#define GRID1 (NB * NK * NCHUNK)    // 1152
#define BLK1 192

// workspace float sizes
#define SZ_CB   (NB * NK * NL * NN)             // 294912
#define SZ_CUMS (NB * NK * NL * NCH)            // 3538944
#define SZ_Y    (NB * NK * NL * NCH)            // 3538944
#define SZ_HEND (NB * NK * NCHUNK * NN * NCH)   // 3538944

// softplus via hw exp2/log2: ~5 VALU ops instead of libcall chain
__device__ __forceinline__ float softplus_fast(float x) {
    float t = exp2f(-fabsf(x) * 1.44269504f);       // v_exp_f32
    float l = __log2f(1.0f + t) * 0.69314718f;      // v_log_f32
    return fmaxf(x, 0.0f) + l;
}

// ============ K1: proj GEMM + delta + chunk-local scan (prep-free)
// Outputs: Cbuf[bk][l][16], cumS[bk][l][c] (inclusive), ybuf[bk][l][c] = y_local,
//          Hend[bk][chk][n][c]
__global__ __launch_bounds__(BLK1) void k_projscan(const float* __restrict__ x,
                                                   const float* __restrict__ xpw,
                                                   const float* __restrict__ dtw,
                                                   const float* __restrict__ dtb,
                                                   const float* __restrict__ A_logs,
                                                   const float* __restrict__ Ds,
                                                   float* __restrict__ Cbuf,
                                                   float* __restrict__ cumS,
                                                   float* __restrict__ ybuf,
                                                   float* __restrict__ Hend) {
    int bid = blockIdx.x, tid = threadIdx.x;
    int bk = bid / NCHUNK, chk = bid % NCHUNK;
    int lt0 = chk * CLEN;
    int b = bk >> 2, k = bk & 3;
    // MAC map: 88 threads, each 4l x 2d
    int dg = tid % 22;                         // d pair: d = dg*2, dg*2+1
    int lt = tid / 22;                         // 0..3 (l-group of 4) for tid<88
    __shared__ float WL[96 * 46];              // [cc][d] pad 46 (float2 align) 17.7 KB
    __shared__ float XS[96 * CLEN];            // [cc][l]   6.1 KB
    __shared__ float DT[CLEN * NR];
    __shared__ float BL[CLEN * NN];
    __shared__ float CL[CLEN * NN];            // total ~26 KB
    const float* bx = x + (size_t)b * NCH * NL;
    bool rev = (k >= 2), tr = (k & 1);
    float acc[4][2];
#pragma unroll
    for (int i = 0; i < 4; ++i) { acc[i][0] = 0.f; acc[i][1] = 0.f; }
    float uvv[CLEN];                           // u captured from XS
    int c = tid;                               // tail channel identity
    int myph = c / 96, mycc = c % 96;
    for (int ph = 0; ph < 2; ++ph) {
        int c0 = ph * 96;
        __syncthreads();
        // stage W: [cc][46], coalesced global along cc
        for (int i = tid; i < ND * 96; i += BLK1) {
            int d = i / 96, cc = i % 96;
            WL[cc * 46 + d] = xpw[((size_t)k * ND + d) * NCH + c0 + cc];
        }
        // stage X: [cc][16]
        for (int i = tid; i < 96 * CLEN; i += BLK1) {
            int cc = i >> 4, j = i & 15;
            int gl = rev ? (NL - 1 - lt0 - j) : (lt0 + j);
            int pos = tr ? ((gl % 48) * 48 + gl / 48) : gl;
            XS[cc * 16 + j] = bx[(size_t)(c0 + cc) * NL + pos];
        }
        __syncthreads();
        if (tid < 88) {
#pragma unroll 8
            for (int cc = 0; cc < 96; ++cc) {
                float4 xv = *(const float4*)&XS[cc * 16 + lt * 4];
                float2 wv = *(const float2*)&WL[cc * 46 + dg * 2];
                acc[0][0] = fmaf(xv.x, wv.x, acc[0][0]);
                acc[0][1] = fmaf(xv.x, wv.y, acc[0][1]);
                acc[1][0] = fmaf(xv.y, wv.x, acc[1][0]);
                acc[1][1] = fmaf(xv.y, wv.y, acc[1][1]);
                acc[2][0] = fmaf(xv.z, wv.x, acc[2][0]);
                acc[2][1] = fmaf(xv.z, wv.y, acc[2][1]);
                acc[3][0] = fmaf(xv.w, wv.x, acc[3][0]);
                acc[3][1] = fmaf(xv.w, wv.y, acc[3][1]);
            }
        }
        // capture u for the tail (skewed: 2-way banks instead of 32-way)
        if (ph == myph) {
#pragma unroll
            for (int ii = 0; ii < CLEN; ++ii) {
                int i2 = (ii + mycc) & 15;
                uvv[i2] = XS[mycc * 16 + i2];
            }
        }
    }
    __syncthreads();
    if (tid < 88) {
#pragma unroll
        for (int li = 0; li < 4; ++li) {
            int l = lt * 4 + li;
#pragma unroll
            for (int e = 0; e < 2; ++e) {
                int d = dg * 2 + e;
                float v = acc[li][e];
                if (d < NR) DT[l * NR + d] = v;
                else if (d < NR + NN) BL[l * NN + (d - NR)] = v;
                else {
                    CL[l * NN + (d - NR - NN)] = v;
                    Cbuf[((size_t)bk * NL + lt0 + l) * NN + (d - NR - NN)] = v;
                }
            }
        }
    }
    __syncthreads();
    {
        float A2[NN];
        {
            const float4* ap = (const float4*)(A_logs + ((size_t)(k * NCH + c)) * NN);
            float4 a0 = ap[0], a1 = ap[1], a2 = ap[2], a3 = ap[3];
            float t16[16] = {a0.x, a0.y, a0.z, a0.w, a1.x, a1.y, a1.z, a1.w,
                             a2.x, a2.y, a2.z, a2.w, a3.x, a3.y, a3.z, a3.w};
#pragma unroll
            for (int n = 0; n < NN; ++n) A2[n] = -__expf(t16[n]) * 1.44269504f;
        }
        const float4* wp = (const float4*)(dtw + ((size_t)k * NCH + c) * NR);
        float4 w0 = wp[0], w1 = wp[1], w2 = wp[2];
        float bias = dtb[k * NCH + c];
        float dval = Ds[k * NCH + c];
        float* csp = cumS + (size_t)bk * NL * NCH + c;
        float sp[CLEN];
        float S = 0.0f;
#pragma unroll
        for (int i = 0; i < CLEN; ++i) {
            float4 a0 = *(const float4*)&DT[i * NR + 0];
            float4 a1 = *(const float4*)&DT[i * NR + 4];
            float4 a2 = *(const float4*)&DT[i * NR + 8];
            float p0 = fmaf(w0.x, a0.x, fmaf(w0.y, a0.y, bias));
            float p1 = fmaf(w0.z, a0.z, w0.w * a0.w);
            float p2 = fmaf(w1.x, a1.x, fmaf(w1.y, a1.y, w1.z * a1.z));
            float p3 = fmaf(w1.w, a1.w, fmaf(w2.x, a2.x, w2.y * a2.y));
            float p4 = fmaf(w2.z, a2.z, w2.w * a2.w);
            float acc2 = (p0 + p1) + (p2 + p3) + p4;
            float s = softplus_fast(acc2);
            sp[i] = s;
            S += s;
            csp[(size_t)(lt0 + i) * NCH] = S;
        }
        float h[NN];
#pragma unroll
        for (int n = 0; n < NN; ++n) h[n] = 0.0f;
        float* yp = ybuf + ((size_t)bk * NL + lt0) * NCH + c;
#pragma unroll 4
        for (int i = 0; i < CLEN; ++i) {
            float du = sp[i] * uvv[i];
            const float4* br = (const float4*)&BL[i * NN];
            float4 b0 = br[0], b1 = br[1], b2 = br[2], b3 = br[3];
            float Bv[16] = {b0.x, b0.y, b0.z, b0.w, b1.x, b1.y, b1.z, b1.w,
                            b2.x, b2.y, b2.z, b2.w, b3.x, b3.y, b3.z, b3.w};
            const float4* cr = (const float4*)&CL[i * NN];
            float4 c0v = cr[0], c1 = cr[1], c2 = cr[2], c3 = cr[3];
            float Cv[16] = {c0v.x, c0v.y, c0v.z, c0v.w, c1.x, c1.y, c1.z, c1.w,
                            c2.x, c2.y, c2.z, c2.w, c3.x, c3.y, c3.z, c3.w};
            float y = 0.0f;
#pragma unroll
            for (int n = 0; n < NN; ++n) {
                float dA = exp2f(sp[i] * A2[n]);
                h[n] = fmaf(dA, h[n], du * Bv[n]);
                y = fmaf(h[n], Cv[n], y);
            }
            y = fmaf(dval, uvv[i], y);
            yp[(size_t)i * NCH] = y;
        }
        // Hend[bk][chk][n][c] — coalesced stores
        size_t ob = (((size_t)bk * NCHUNK + chk) * NN) * NCH + c;
#pragma unroll
        for (int n = 0; n < NN; ++n)
            Hend[ob + (size_t)n * NCH] = h[n];
    }
}

// ============ K2: cross-chunk prefix in place (Hend -> Hin), 384 blocks x 64
__global__ __launch_bounds__(64) void k_s2(const float* __restrict__ cumS,
                                           const float* __restrict__ A_logs,
                                           float* __restrict__ Hend) {
    int g = blockIdx.x * 64 + threadIdx.x;     // 0..24575
    int bk = g / (NCH * NN);
    int cn = g % (NCH * NN);
    int n = cn / NCH, c = cn % NCH;            // c fastest -> coalesced
    int k = bk & 3;
    float A2 = -__expf(A_logs[((size_t)(k * NCH + c)) * NN + n]) * 1.44269504f;
    float h = 0.0f;
    const float* csp = cumS + (size_t)bk * NL * NCH + c;
    for (int j = 0; j < NCHUNK; ++j) {
        float S = csp[(size_t)(j * CLEN + CLEN - 1) * NCH];
        size_t idx = (((size_t)bk * NCHUNK + j) * NN + n) * NCH + c;
        float E = Hend[idx];
        float P = exp2f(S * A2);
        Hend[idx] = h;
        h = fmaf(P, h, E);
    }
}

// ============ K3: fused correction + cross-merge, 384 blocks x 192
__global__ __launch_bounds__(BLK1) void k_fixmerge(const float* __restrict__ ybuf,
                                                   const float* __restrict__ Cbuf,
                                                   const float* __restrict__ cumS,
                                                   const float* __restrict__ Hin,
                                                   const float* __restrict__ A_logs,
                                                   float* __restrict__ out) {
    int bid = blockIdx.x;
    int mb = bid / 192;
    int rem = bid % 192;
    int hh = rem / 4;
    int q = rem % 4;
    int c = threadIdx.x;                       // 0..191
    float accw[12];
#pragma unroll
    for (int w = 0; w < 12; ++w) accw[w] = 0.0f;
#pragma unroll
    for (int k = 0; k < NK; ++k) {
        int bk = mb * NK + k;
        float A2[NN];
        {
            const float4* ap = (const float4*)(A_logs + ((size_t)(k * NCH + c)) * NN);
            float4 a0 = ap[0], a1 = ap[1], a2 = ap[2], a3 = ap[3];
            float t16[16] = {a0.x, a0.y, a0.z, a0.w, a1.x, a1.y, a1.z, a1.w,
                             a2.x, a2.y, a2.z, a2.w, a3.x, a3.y, a3.z, a3.w};
#pragma unroll
            for (int n = 0; n < NN; ++n) A2[n] = -__expf(t16[n]) * 1.44269504f;
        }
        const float* yb = ybuf + (size_t)bk * NL * NCH;
        const float* cs = cumS + (size_t)bk * NL * NCH;
        const float* cb = Cbuf + (size_t)bk * NL * NN;
        const float* hb = Hin + (size_t)bk * NCHUNK * NN * NCH;
        for (int w = 0; w < 12; ++w) {
            int s_hw = hh * NW + q * 12 + w;
            int s_wh = (q * 12 + w) * NH + hh;
            int sp = (k & 1) ? s_wh : s_hw;
            int l = (k >= 2) ? (NL - 1 - sp) : sp;
            float csv = cs[(size_t)l * NCH + c];
            const float4* cr = (const float4*)(cb + (size_t)l * NN);
            float4 c0 = cr[0], c1 = cr[1], c2 = cr[2], c3 = cr[3];
            float Cv[16] = {c0.x, c0.y, c0.z, c0.w, c1.x, c1.y, c1.z, c1.w,
                            c2.x, c2.y, c2.z, c2.w, c3.x, c3.y, c3.z, c3.w};
            const float* hp = hb + ((size_t)(l / CLEN) * NN) * NCH + c;
            float v = yb[(size_t)l * NCH + c];
#pragma unroll
            for (int n = 0; n < NN; ++n) {
                float e = exp2f(csv * A2[n]);
                v = fmaf(Cv[n] * hp[(size_t)n * NCH], e, v);
            }
            accw[w] += v;
        }
    }
    float* op = out + ((size_t)(mb * NCH + c)) * NL + hh * NW + q * 12;
#pragma unroll
    for (int w = 0; w < 12; ++w) op[w] = accw[w];
}

extern "C" void kernel_launch(void* const* d_in, const int* in_sizes, int n_in,
                              void* d_out, int out_size, void* d_ws, size_t ws_size,
                              hipStream_t stream) {
    const float* x      = (const float*)d_in[0];
    const float* xpw    = (const float*)d_in[1];
    const float* dtw    = (const float*)d_in[2];
    const float* A_logs = (const float*)d_in[3];
    const float* Ds     = (const float*)d_in[4];
    const float* dtb    = (const float*)d_in[5];
    float* out = (float*)d_out;

    float* ws = (float*)d_ws;
    float* Cbuf = ws;
    float* cumS = Cbuf + SZ_CB;
    float* ybuf = cumS + SZ_CUMS;
    float* Hend = ybuf + SZ_Y;     // k_s2 rewrites in place to Hin

    k_projscan<<<GRID1, BLK1, 0, stream>>>(x, xpw, dtw, dtb, A_logs, Ds,
                                           Cbuf, cumS, ybuf, Hend);
    k_s2<<<384, 64, 0, stream>>>(cumS, A_logs, Hend);
    k_fixmerge<<<384, BLK1, 0, stream>>>(ybuf, Cbuf, cumS, Hend, A_logs, out);
}